// Round 4
// baseline (98.337 us; speedup 1.0000x reference)
//
#include <hip/hip_runtime.h>
#include <hip/hip_bf16.h>

typedef __attribute__((ext_vector_type(8))) short short8;
typedef __attribute__((ext_vector_type(4))) float f32x4;

#define B_DIM   8192
#define IN_DIM  2048
#define OUT_DIM 1024
#define K_DIM   (2 * IN_DIM)   // 4096: [masked x | -|x|] concat along K

#define BM 256
#define BN 128
#define BK 64
#define NT (K_DIM / BK)            // 64 K-tiles
#define A_TILE_E (BM * BK)         // 16384 bf16 = 32 KB
#define B_TILE_E (BN * BK)         // 8192  bf16 = 16 KB
#define NBUF 3
#define LDS_BYTES ((A_TILE_E + B_TILE_E) * NBUF * 2)   // 144 KiB

__device__ __forceinline__ unsigned short f2bf(float f) {
    union { float f; unsigned u; } v; v.f = f;
    unsigned u = v.u;
    unsigned r = (u + 0x7FFFu + ((u >> 16) & 1u)) >> 16;   // RNE
    return (unsigned short)r;
}

// A'[b][i] = x[b][i] if x >= -1 else 0 ; A'[b][IN+i] = -|x[b][i]|
__global__ void prep_x(const float* __restrict__ x, unsigned short* __restrict__ A) {
    const int n8 = B_DIM * IN_DIM / 8;
    for (int v = blockIdx.x * blockDim.x + threadIdx.x; v < n8;
         v += gridDim.x * blockDim.x) {
        const float4* xp = reinterpret_cast<const float4*>(x) + (size_t)v * 2;
        float4 lo = xp[0], hi = xp[1];
        float xs[8] = {lo.x, lo.y, lo.z, lo.w, hi.x, hi.y, hi.z, hi.w};
        short8 mv, av;
        #pragma unroll
        for (int j = 0; j < 8; ++j) {
            float xf = xs[j];
            mv[j] = (short)f2bf(xf >= -1.0f ? xf : 0.0f);
            av[j] = (short)f2bf(-fabsf(xf));
        }
        int b  = v >> 8;
        int i8 = v & 255;
        *reinterpret_cast<short8*>(A + (size_t)b * K_DIM + i8 * 8)          = mv;
        *reinterpret_cast<short8*>(A + (size_t)b * K_DIM + IN_DIM + i8 * 8) = av;
    }
}

// Bt[o][i] = W[i][o] ; Bt[o][IN+i] = 0.1*|W[i][o]|
__global__ void prep_w(const float* __restrict__ W, unsigned short* __restrict__ Bt) {
    __shared__ float tile[32][33];
    int o0 = blockIdx.x * 32;
    int i0 = blockIdx.y * 32;
    int tx = threadIdx.x, ty = threadIdx.y;   // 32 x 8
    #pragma unroll
    for (int r = 0; r < 4; ++r) {
        int ii = ty + r * 8;
        tile[ii][tx] = W[(size_t)(i0 + ii) * OUT_DIM + o0 + tx];
    }
    __syncthreads();
    #pragma unroll
    for (int r = 0; r < 4; ++r) {
        int oo = ty + r * 8;
        float wv = tile[tx][oo];
        Bt[(size_t)(o0 + oo) * K_DIM + i0 + tx]          = f2bf(wv);
        Bt[(size_t)(o0 + oo) * K_DIM + IN_DIM + i0 + tx] = f2bf(0.1f * fabsf(wv));
    }
}

// staging: linear LDS dest, XOR-swizzled global SOURCE slot (rule 21)
__device__ __forceinline__ void stage_round(const unsigned short* __restrict__ gsrc,
                                            unsigned short* lds_base,
                                            int row_base, int k0, int r, int tid) {
    int c    = r * 512 + tid;
    int row  = c >> 3;
    int slot = (c & 7) ^ (row & 7);
    __builtin_amdgcn_global_load_lds(
        (const __attribute__((address_space(1))) void*)(gsrc + (size_t)(row_base + row) * K_DIM + k0 + slot * 8),
        (__attribute__((address_space(3))) void*)(lds_base + (size_t)c * 8),
        16, 0, 0);
}

// inverse-swizzled fragment read (same involution as stage source)
__device__ __forceinline__ short8 read_frag(const unsigned short* buf, int row,
                                            int kk, int lq) {
    int sl = (kk * 4 + lq) ^ (row & 7);
    return *reinterpret_cast<const short8*>(buf + row * BK + (sl << 3));
}

#define PHASE_ENTER() do {                                    \
    __builtin_amdgcn_s_barrier();                             \
    asm volatile("s_waitcnt lgkmcnt(0)" ::: "memory");        \
    __builtin_amdgcn_sched_barrier(0);                        \
    __builtin_amdgcn_s_setprio(1); } while (0)

#define PHASE_EXIT() do {                                     \
    __builtin_amdgcn_s_setprio(0);                            \
    __builtin_amdgcn_s_barrier(); } while (0)

// out[b][o] = sum_k A'[b][k] * Bt[o][k] + 1e-5
__global__ __launch_bounds__(512, 2) void gemm_fused(const unsigned short* __restrict__ A,
                                                     const unsigned short* __restrict__ Bt,
                                                     float* __restrict__ C) {
    extern __shared__ __align__(16) unsigned short smem[];
    unsigned short* sA = smem;                       // [3][16384]
    unsigned short* sB = smem + NBUF * A_TILE_E;     // [3][8192]

    // XCD colocation (R3, verified: FETCH at compulsory minimum)
    int bid = blockIdx.x;
    int xcd = bid & 7;
    int idx = bid >> 3;            // 0..31
    int by  = xcd * 4 + (idx >> 3);
    int bx  = idx & 7;
    int row0 = by * BM;
    int col0 = bx * BN;

    int tid  = threadIdx.x;
    int lane = tid & 63;
    int w    = tid >> 6;           // 0..7
    int wr   = w >> 1;             // 0..3
    int wc   = w & 1;              // 0..1
    int lr   = lane & 15;
    int lq   = lane >> 4;          // 0..3
    int rowA = wr * 64 + lr;       // + m*16
    int rowB = wc * 64 + lr;       // + n*16

    f32x4 acc[4][4];
    #pragma unroll
    for (int m = 0; m < 4; ++m)
        #pragma unroll
        for (int n = 0; n < 4; ++n)
            acc[m][n] = (f32x4){0.f, 0.f, 0.f, 0.f};

    // prologue: stage tiles 0 and 1
    #pragma unroll
    for (int r = 0; r < 4; ++r) stage_round(A,  sA,            row0, 0,  r, tid);
    #pragma unroll
    for (int r = 0; r < 2; ++r) stage_round(Bt, sB,            col0, 0,  r, tid);
    #pragma unroll
    for (int r = 0; r < 4; ++r) stage_round(A,  sA + A_TILE_E, row0, BK, r, tid);
    #pragma unroll
    for (int r = 0; r < 2; ++r) stage_round(Bt, sB + B_TILE_E, col0, BK, r, tid);
    asm volatile("s_waitcnt vmcnt(6)" ::: "memory");
    __builtin_amdgcn_s_barrier();

    int c = 0;
    for (int t = 0; t < NT; ++t) {
        unsigned short* bufA = sA + c * A_TILE_E;
        unsigned short* bufB = sB + c * B_TILE_E;
        unsigned short* pfA;
        unsigned short* pfB;
        {
            int c2 = c + 2; if (c2 >= NBUF) c2 -= NBUF;
            pfA = sA + c2 * A_TILE_E;
            pfB = sB + c2 * B_TILE_E;
        }
        int k2 = (t + 2) * BK;
        bool pf = (t + 2) < NT;

        short8 a01[2][2], a23[2][2], b01[2][2], b23[2][2];

        // ---- P0: quadrant m01 x n01 ----
        #pragma unroll
        for (int m = 0; m < 2; ++m)
            #pragma unroll
            for (int kk = 0; kk < 2; ++kk)
                a01[m][kk] = read_frag(bufA, rowA + m * 16, kk, lq);
        #pragma unroll
        for (int n = 0; n < 2; ++n)
            #pragma unroll
            for (int kk = 0; kk < 2; ++kk)
                b01[n][kk] = read_frag(bufB, rowB + n * 16, kk, lq);
        if (pf) {
            stage_round(A, pfA, row0, k2, 0, tid);
            stage_round(A, pfA, row0, k2, 1, tid);
        }
        PHASE_ENTER();
        #pragma unroll
        for (int kk = 0; kk < 2; ++kk)
            #pragma unroll
            for (int m = 0; m < 2; ++m)
                #pragma unroll
                for (int n = 0; n < 2; ++n)
                    acc[m][n] = __builtin_amdgcn_mfma_f32_16x16x32_bf16(
                        a01[m][kk], b01[n][kk], acc[m][n], 0, 0, 0);
        PHASE_EXIT();

        // ---- P1: quadrant m01 x n23 ----
        #pragma unroll
        for (int n = 0; n < 2; ++n)
            #pragma unroll
            for (int kk = 0; kk < 2; ++kk)
                b23[n][kk] = read_frag(bufB, rowB + (n + 2) * 16, kk, lq);
        if (pf) {
            stage_round(A, pfA, row0, k2, 2, tid);
            stage_round(A, pfA, row0, k2, 3, tid);
        }
        PHASE_ENTER();
        #pragma unroll
        for (int kk = 0; kk < 2; ++kk)
            #pragma unroll
            for (int m = 0; m < 2; ++m)
                #pragma unroll
                for (int n = 0; n < 2; ++n)
                    acc[m][n + 2] = __builtin_amdgcn_mfma_f32_16x16x32_bf16(
                        a01[m][kk], b23[n][kk], acc[m][n + 2], 0, 0, 0);
        PHASE_EXIT();

        // ---- P2: quadrant m23 x n23 ----
        #pragma unroll
        for (int m = 0; m < 2; ++m)
            #pragma unroll
            for (int kk = 0; kk < 2; ++kk)
                a23[m][kk] = read_frag(bufA, rowA + (m + 2) * 16, kk, lq);
        if (pf) stage_round(Bt, pfB, col0, k2, 0, tid);
        PHASE_ENTER();
        #pragma unroll
        for (int kk = 0; kk < 2; ++kk)
            #pragma unroll
            for (int m = 0; m < 2; ++m)
                #pragma unroll
                for (int n = 0; n < 2; ++n)
                    acc[m + 2][n + 2] = __builtin_amdgcn_mfma_f32_16x16x32_bf16(
                        a23[m][kk], b23[n][kk], acc[m + 2][n + 2], 0, 0, 0);
        PHASE_EXIT();

        // ---- P3: quadrant m23 x n01 (no new frags) ----
        if (pf) {
            stage_round(Bt, pfB, col0, k2, 1, tid);
            asm volatile("s_waitcnt vmcnt(6)" ::: "memory");   // t+1 resident, t+2 in flight
        } else {
            asm volatile("s_waitcnt vmcnt(0)" ::: "memory");
        }
        PHASE_ENTER();
        #pragma unroll
        for (int kk = 0; kk < 2; ++kk)
            #pragma unroll
            for (int m = 0; m < 2; ++m)
                #pragma unroll
                for (int n = 0; n < 2; ++n)
                    acc[m + 2][n] = __builtin_amdgcn_mfma_f32_16x16x32_bf16(
                        a23[m][kk], b01[n][kk], acc[m + 2][n], 0, 0, 0);
        PHASE_EXIT();

        c += 1; if (c >= NBUF) c -= NBUF;
    }

    // epilogue: C/D layout col = lane&15, row = (lane>>4)*4 + reg
    #pragma unroll
    for (int m = 0; m < 4; ++m) {
        #pragma unroll
        for (int n = 0; n < 4; ++n) {
            int col  = col0 + wc * 64 + n * 16 + lr;
            int rowb = row0 + wr * 64 + m * 16 + lq * 4;
            #pragma unroll
            for (int j = 0; j < 4; ++j)
                C[(size_t)(rowb + j) * OUT_DIM + col] = acc[m][n][j] + 1e-5f;
        }
    }
}

extern "C" void kernel_launch(void* const* d_in, const int* in_sizes, int n_in,
                              void* d_out, int out_size, void* d_ws, size_t ws_size,
                              hipStream_t stream) {
    const float* x = (const float*)d_in[0];
    const float* W = (const float*)d_in[1];
    float* out = (float*)d_out;

    unsigned short* A  = (unsigned short*)d_ws;                              // 64 MB
    unsigned short* Bt = (unsigned short*)d_ws + (size_t)B_DIM * K_DIM;      // + 8 MB

    (void)hipFuncSetAttribute((const void*)gemm_fused,
                              hipFuncAttributeMaxDynamicSharedMemorySize, LDS_BYTES);

    prep_x<<<4096, 256, 0, stream>>>(x, A);
    prep_w<<<dim3(OUT_DIM / 32, IN_DIM / 32), dim3(32, 8), 0, stream>>>(W, Bt);
    gemm_fused<<<(B_DIM / BM) * (OUT_DIM / BN), 512, LDS_BYTES, stream>>>(A, Bt, out);
}

// Round 5
// 95.021 us; speedup vs baseline: 1.0349x; 1.0349x over previous
//
#include <hip/hip_runtime.h>
#include <hip/hip_bf16.h>

typedef __attribute__((ext_vector_type(8))) short short8;
typedef __attribute__((ext_vector_type(4))) float f32x4;

#define B_DIM   8192
#define IN_DIM  2048
#define OUT_DIM 1024
#define K_DIM   (2 * IN_DIM)   // 4096: [masked x | -|x|] concat along K

#define BM 256
#define BN 128
#define BK 64
#define NT (K_DIM / BK)            // 64 K-tiles
#define A_TILE_E (BM * BK)         // 16384 bf16 = 32 KB
#define B_TILE_E (BN * BK)         // 8192  bf16 = 16 KB
#define NBUF 3
#define LDS_BYTES ((A_TILE_E + B_TILE_E) * NBUF * 2)   // 144 KiB

__device__ __forceinline__ unsigned short f2bf(float f) {
    union { float f; unsigned u; } v; v.f = f;
    unsigned u = v.u;
    unsigned r = (u + 0x7FFFu + ((u >> 16) & 1u)) >> 16;   // RNE
    return (unsigned short)r;
}

// A'[b][i] = x[b][i] if x >= -1 else 0 ; A'[b][IN+i] = -|x[b][i]|
__global__ void prep_x(const float* __restrict__ x, unsigned short* __restrict__ A) {
    const int n8 = B_DIM * IN_DIM / 8;
    for (int v = blockIdx.x * blockDim.x + threadIdx.x; v < n8;
         v += gridDim.x * blockDim.x) {
        const float4* xp = reinterpret_cast<const float4*>(x) + (size_t)v * 2;
        float4 lo = xp[0], hi = xp[1];
        float xs[8] = {lo.x, lo.y, lo.z, lo.w, hi.x, hi.y, hi.z, hi.w};
        short8 mv, av;
        #pragma unroll
        for (int j = 0; j < 8; ++j) {
            float xf = xs[j];
            mv[j] = (short)f2bf(xf >= -1.0f ? xf : 0.0f);
            av[j] = (short)f2bf(-fabsf(xf));
        }
        int b  = v >> 8;
        int i8 = v & 255;
        *reinterpret_cast<short8*>(A + (size_t)b * K_DIM + i8 * 8)          = mv;
        *reinterpret_cast<short8*>(A + (size_t)b * K_DIM + IN_DIM + i8 * 8) = av;
    }
}

// Bt[o][i] = W[i][o] ; Bt[o][IN+i] = 0.1*|W[i][o]|
__global__ void prep_w(const float* __restrict__ W, unsigned short* __restrict__ Bt) {
    __shared__ float tile[32][33];
    int o0 = blockIdx.x * 32;
    int i0 = blockIdx.y * 32;
    int tx = threadIdx.x, ty = threadIdx.y;   // 32 x 8
    #pragma unroll
    for (int r = 0; r < 4; ++r) {
        int ii = ty + r * 8;
        tile[ii][tx] = W[(size_t)(i0 + ii) * OUT_DIM + o0 + tx];
    }
    __syncthreads();
    #pragma unroll
    for (int r = 0; r < 4; ++r) {
        int oo = ty + r * 8;
        float wv = tile[tx][oo];
        Bt[(size_t)(o0 + oo) * K_DIM + i0 + tx]          = f2bf(wv);
        Bt[(size_t)(o0 + oo) * K_DIM + IN_DIM + i0 + tx] = f2bf(0.1f * fabsf(wv));
    }
}

// staging: linear LDS dest, XOR-swizzled global SOURCE slot (rule 21)
// 256 threads x 16B = 4 KB per round; A tile = 8 rounds, B tile = 4 rounds
__device__ __forceinline__ void stage_round(const unsigned short* __restrict__ gsrc,
                                            unsigned short* lds_base,
                                            int row_base, int k0, int r, int tid) {
    int c    = r * 256 + tid;
    int row  = c >> 3;
    int slot = (c & 7) ^ (row & 7);
    __builtin_amdgcn_global_load_lds(
        (const __attribute__((address_space(1))) void*)(gsrc + (size_t)(row_base + row) * K_DIM + k0 + slot * 8),
        (__attribute__((address_space(3))) void*)(lds_base + (size_t)c * 8),
        16, 0, 0);
}

// inverse-swizzled fragment read (same involution as stage source)
__device__ __forceinline__ short8 read_frag(const unsigned short* buf, int row,
                                            int kk, int lq) {
    int sl = (kk * 4 + lq) ^ (row & 7);
    return *reinterpret_cast<const short8*>(buf + row * BK + (sl << 3));
}

#define PHASE_ENTER() do {                                    \
    __builtin_amdgcn_s_barrier();                             \
    asm volatile("s_waitcnt lgkmcnt(0)" ::: "memory");        \
    __builtin_amdgcn_sched_barrier(0);                        \
    __builtin_amdgcn_s_setprio(1); } while (0)

#define PHASE_EXIT() do {                                     \
    __builtin_amdgcn_s_setprio(0);                            \
    __builtin_amdgcn_s_barrier(); } while (0)

// out[b][o] = sum_k A'[b][k] * Bt[o][k] + 1e-5
// 4 waves, each owns a 128x64 output sub-tile (m201 per-wave geometry)
__global__ __launch_bounds__(256) void gemm_fused(const unsigned short* __restrict__ A,
                                                  const unsigned short* __restrict__ Bt,
                                                  float* __restrict__ C) {
    extern __shared__ __align__(16) unsigned short smem[];
    unsigned short* sA = smem;                       // [3][16384]
    unsigned short* sB = smem + NBUF * A_TILE_E;     // [3][8192]

    // XCD colocation (R3-verified: FETCH at compulsory minimum)
    int bid = blockIdx.x;
    int xcd = bid & 7;
    int idx = bid >> 3;            // 0..31
    int by  = xcd * 4 + (idx >> 3);
    int bx  = idx & 7;
    int row0 = by * BM;
    int col0 = bx * BN;

    int tid  = threadIdx.x;
    int lane = tid & 63;
    int w    = tid >> 6;           // 0..3
    int wr   = w >> 1;             // 0..1 : 128-row half
    int wc   = w & 1;              // 0..1 : 64-col half
    int lr   = lane & 15;
    int lq   = lane >> 4;          // 0..3
    int rowA = wr * 128 + lr;      // + m*16, m=0..7
    int rowB = wc * 64 + lr;       // + n*16, n=0..3

    f32x4 acc[8][4];
    #pragma unroll
    for (int m = 0; m < 8; ++m)
        #pragma unroll
        for (int n = 0; n < 4; ++n)
            acc[m][n] = (f32x4){0.f, 0.f, 0.f, 0.f};

    // prologue: stage tiles 0 and 1 (12 rounds each)
    #pragma unroll
    for (int r = 0; r < 8; ++r) stage_round(A,  sA,            row0, 0,  r, tid);
    #pragma unroll
    for (int r = 0; r < 4; ++r) stage_round(Bt, sB,            col0, 0,  r, tid);
    #pragma unroll
    for (int r = 0; r < 8; ++r) stage_round(A,  sA + A_TILE_E, row0, BK, r, tid);
    #pragma unroll
    for (int r = 0; r < 4; ++r) stage_round(Bt, sB + B_TILE_E, col0, BK, r, tid);
    asm volatile("s_waitcnt vmcnt(12)" ::: "memory");   // tile 0 resident
    __builtin_amdgcn_s_barrier();

    int c = 0;
    for (int t = 0; t < NT; ++t) {
        unsigned short* bufA = sA + c * A_TILE_E;
        unsigned short* bufB = sB + c * B_TILE_E;
        int c2 = c + 2; if (c2 >= NBUF) c2 -= NBUF;
        unsigned short* pfA = sA + c2 * A_TILE_E;
        unsigned short* pfB = sB + c2 * B_TILE_E;
        int k2 = (t + 2) * BK;
        bool pf = (t + 2) < NT;

        short8 af[8], bf[4];

        // ---------------- phase 0 (kk = 0): 12 reads | 6 stages | 32 MFMA ----
        #pragma unroll
        for (int m = 0; m < 8; ++m) af[m] = read_frag(bufA, rowA + m * 16, 0, lq);
        #pragma unroll
        for (int n = 0; n < 4; ++n) bf[n] = read_frag(bufB, rowB + n * 16, 0, lq);
        if (pf) {
            stage_round(A, pfA, row0, k2, 0, tid);
            stage_round(A, pfA, row0, k2, 1, tid);
            stage_round(A, pfA, row0, k2, 2, tid);
            stage_round(A, pfA, row0, k2, 3, tid);
            stage_round(A, pfA, row0, k2, 4, tid);
            stage_round(A, pfA, row0, k2, 5, tid);
        }
        PHASE_ENTER();
        #pragma unroll
        for (int m = 0; m < 8; ++m)
            #pragma unroll
            for (int n = 0; n < 4; ++n)
                acc[m][n] = __builtin_amdgcn_mfma_f32_16x16x32_bf16(
                    af[m], bf[n], acc[m][n], 0, 0, 0);
        PHASE_EXIT();

        // ---------------- phase 1 (kk = 1): 12 reads | 6 stages | 32 MFMA ----
        #pragma unroll
        for (int m = 0; m < 8; ++m) af[m] = read_frag(bufA, rowA + m * 16, 1, lq);
        #pragma unroll
        for (int n = 0; n < 4; ++n) bf[n] = read_frag(bufB, rowB + n * 16, 1, lq);
        if (pf) {
            stage_round(A,  pfA, row0, k2, 6, tid);
            stage_round(A,  pfA, row0, k2, 7, tid);
            stage_round(Bt, pfB, col0, k2, 0, tid);
            stage_round(Bt, pfB, col0, k2, 1, tid);
            stage_round(Bt, pfB, col0, k2, 2, tid);
            stage_round(Bt, pfB, col0, k2, 3, tid);
            // t+1 resident, t+2's 12 stay in flight (never drain mid-loop)
            asm volatile("s_waitcnt vmcnt(12)" ::: "memory");
        } else {
            asm volatile("s_waitcnt vmcnt(0)" ::: "memory");
        }
        PHASE_ENTER();
        #pragma unroll
        for (int m = 0; m < 8; ++m)
            #pragma unroll
            for (int n = 0; n < 4; ++n)
                acc[m][n] = __builtin_amdgcn_mfma_f32_16x16x32_bf16(
                    af[m], bf[n], acc[m][n], 0, 0, 0);
        PHASE_EXIT();

        c += 1; if (c >= NBUF) c -= NBUF;
    }

    // epilogue: C/D layout col = lane&15, row = (lane>>4)*4 + reg
    #pragma unroll
    for (int m = 0; m < 8; ++m) {
        #pragma unroll
        for (int n = 0; n < 4; ++n) {
            int col  = col0 + wc * 64 + n * 16 + lr;
            int rowb = row0 + wr * 128 + m * 16 + lq * 4;
            #pragma unroll
            for (int j = 0; j < 4; ++j)
                C[(size_t)(rowb + j) * OUT_DIM + col] = acc[m][n][j] + 1e-5f;
        }
    }
}

extern "C" void kernel_launch(void* const* d_in, const int* in_sizes, int n_in,
                              void* d_out, int out_size, void* d_ws, size_t ws_size,
                              hipStream_t stream) {
    const float* x = (const float*)d_in[0];
    const float* W = (const float*)d_in[1];
    float* out = (float*)d_out;

    unsigned short* A  = (unsigned short*)d_ws;                              // 64 MB
    unsigned short* Bt = (unsigned short*)d_ws + (size_t)B_DIM * K_DIM;      // + 8 MB

    (void)hipFuncSetAttribute((const void*)gemm_fused,
                              hipFuncAttributeMaxDynamicSharedMemorySize, LDS_BYTES);

    prep_x<<<4096, 256, 0, stream>>>(x, A);
    prep_w<<<dim3(OUT_DIM / 32, IN_DIM / 32), dim3(32, 8), 0, stream>>>(W, Bt);
    gemm_fused<<<(B_DIM / BM) * (OUT_DIM / BN), 256, LDS_BYTES, stream>>>(A, Bt, out);
}

// Round 6
// 89.184 us; speedup vs baseline: 1.1026x; 1.0655x over previous
//
#include <hip/hip_runtime.h>
#include <hip/hip_bf16.h>

typedef __attribute__((ext_vector_type(8))) short short8;
typedef __attribute__((ext_vector_type(4))) float f32x4;
typedef __attribute__((ext_vector_type(4))) unsigned int u32x4;

#define B_DIM   8192
#define IN_DIM  2048
#define OUT_DIM 1024

#define BM 256
#define BN 128
#define IS 32                      // i-step per iteration
#define NT2 (IN_DIM / IS)          // 64 iterations
#define A_VAR_E (BM * IS)          // 8192 elems = 16 KB per variant
#define A_BUF_E (2 * A_VAR_E)      // xm + na = 32 KB per buffer
#define B_MAT_E (BN * 64)          // 8192 elems = 16 KB per matrix tile (64-i super-tile)
#define B_BUF_E (2 * B_MAT_E)      // Bw + Ba
#define LDS_BYTES ((2 * A_BUF_E + 2 * B_BUF_E) * 2)   // 131072 = 128 KiB

__device__ __forceinline__ unsigned short f2bf(float f) {
    union { float f; unsigned u; } v; v.f = f;
    unsigned u = v.u;
    unsigned r = (u + 0x7FFFu + ((u >> 16) & 1u)) >> 16;   // RNE
    return (unsigned short)r;
}

// Bw[o][i] = W[i][o] ; Ba[o][i] = 0.1*|W[i][o]|
__global__ void prep_w(const float* __restrict__ W, unsigned short* __restrict__ Bw,
                       unsigned short* __restrict__ Ba) {
    __shared__ float tile[32][33];
    int o0 = blockIdx.x * 32;
    int i0 = blockIdx.y * 32;
    int tx = threadIdx.x, ty = threadIdx.y;   // 32 x 8
    #pragma unroll
    for (int r = 0; r < 4; ++r) {
        int ii = ty + r * 8;
        tile[ii][tx] = W[(size_t)(i0 + ii) * OUT_DIM + o0 + tx];
    }
    __syncthreads();
    #pragma unroll
    for (int r = 0; r < 4; ++r) {
        int oo = ty + r * 8;
        float wv = tile[tx][oo];
        Bw[(size_t)(o0 + oo) * IN_DIM + i0 + tx] = f2bf(wv);
        Ba[(size_t)(o0 + oo) * IN_DIM + i0 + tx] = f2bf(0.1f * fabsf(wv));
    }
}

// B staging: linear LDS dest, XOR-swizzled global SOURCE slot (rule 21).
// One 128x64 tile = 16 KB = 2 rounds of 512 threads x 16 B.
__device__ __forceinline__ void stageB(const unsigned short* __restrict__ g,
                                       unsigned short* lds_dst,
                                       int col0, int i0, int r, int tid) {
    int c    = r * 512 + tid;                // 0..1023
    int row  = c >> 3;                       // 0..127
    int slot = (c & 7) ^ (row & 7);
    __builtin_amdgcn_global_load_lds(
        (const __attribute__((address_space(1))) void*)(g + (size_t)(col0 + row) * IN_DIM + i0 + slot * 8),
        (__attribute__((address_space(3))) void*)(lds_dst + (size_t)c * 8),
        16, 0, 0);
}

// A-frag read: swizzle S(r) = (r ^ (r>>2)) & 3 (2-way-free on read & write)
__device__ __forceinline__ short8 read_afrag(const unsigned short* bufA, int var,
                                             int ra, int lq) {
    int sl = lq ^ ((ra ^ (ra >> 2)) & 3);
    return *reinterpret_cast<const short8*>(bufA + var * A_VAR_E + ra * IS + sl * 8);
}

// B-frag read: R3-proven 8-slot swizzle
__device__ __forceinline__ short8 read_bfrag(const unsigned short* bufB, int var,
                                             int rb, int kk, int lq) {
    int sl = (kk * 4 + lq) ^ (rb & 7);
    return *reinterpret_cast<const short8*>(bufB + var * B_MAT_E + rb * 64 + sl * 8);
}

// ---- per-iteration macros (expand in kernel scope; rely on ambient names) ----
#define ISSUE_X(SET, TT) do {                                                   \
    const float4* p_ = reinterpret_cast<const float4*>(                         \
        x + (size_t)(row0 + r_) * IN_DIM + (TT) * IS + xcol_);                  \
    SET[0] = p_[0]; SET[1] = p_[1]; SET[2] = p_[2]; SET[3] = p_[3]; } while (0)

#define CVT_STORE(SET, DST) do {                                                \
    unsigned xm_d[8], na_d[8];                                                  \
    _Pragma("unroll")                                                           \
    for (int q_ = 0; q_ < 4; ++q_) {                                            \
        float4 v_ = SET[q_];                                                    \
        float m0_ = v_.x >= -1.0f ? v_.x : 0.0f;                                \
        float m1_ = v_.y >= -1.0f ? v_.y : 0.0f;                                \
        float m2_ = v_.z >= -1.0f ? v_.z : 0.0f;                                \
        float m3_ = v_.w >= -1.0f ? v_.w : 0.0f;                                \
        float n0_ = -fabsf(v_.x), n1_ = -fabsf(v_.y);                           \
        float n2_ = -fabsf(v_.z), n3_ = -fabsf(v_.w);                           \
        asm("v_cvt_pk_bf16_f32 %0, %1, %2" : "=v"(xm_d[q_*2  ]) : "v"(m0_), "v"(m1_)); \
        asm("v_cvt_pk_bf16_f32 %0, %1, %2" : "=v"(xm_d[q_*2+1]) : "v"(m2_), "v"(m3_)); \
        asm("v_cvt_pk_bf16_f32 %0, %1, %2" : "=v"(na_d[q_*2  ]) : "v"(n0_), "v"(n1_)); \
        asm("v_cvt_pk_bf16_f32 %0, %1, %2" : "=v"(na_d[q_*2+1]) : "v"(n2_), "v"(n3_)); \
    }                                                                           \
    u32x4 xlo_ = {xm_d[0], xm_d[1], xm_d[2], xm_d[3]};                          \
    u32x4 xhi_ = {xm_d[4], xm_d[5], xm_d[6], xm_d[7]};                          \
    u32x4 nlo_ = {na_d[0], na_d[1], na_d[2], na_d[3]};                          \
    u32x4 nhi_ = {na_d[4], na_d[5], na_d[6], na_d[7]};                          \
    *reinterpret_cast<u32x4*>((DST)            + offA0_) = xlo_;                \
    *reinterpret_cast<u32x4*>((DST)            + offA1_) = xhi_;                \
    *reinterpret_cast<u32x4*>((DST) + A_VAR_E  + offA0_) = nlo_;                \
    *reinterpret_cast<u32x4*>((DST) + A_VAR_E  + offA1_) = nhi_; } while (0)

#define FRAGS_MFMA(BA, BB, KK) do {                                             \
    short8 fxm_[4], fna_[4], fbw_[4], fba_[4];                                  \
    _Pragma("unroll")                                                           \
    for (int m_ = 0; m_ < 4; ++m_) {                                            \
        fxm_[m_] = read_afrag((BA), 0, rowA + m_ * 16, lq);                     \
        fna_[m_] = read_afrag((BA), 1, rowA + m_ * 16, lq);                     \
    }                                                                           \
    _Pragma("unroll")                                                           \
    for (int n_ = 0; n_ < 4; ++n_) {                                            \
        fbw_[n_] = read_bfrag((BB), 0, rowB + n_ * 16, (KK), lq);               \
        fba_[n_] = read_bfrag((BB), 1, rowB + n_ * 16, (KK), lq);               \
    }                                                                           \
    __builtin_amdgcn_s_setprio(1);                                              \
    _Pragma("unroll")                                                           \
    for (int m_ = 0; m_ < 4; ++m_)                                              \
        _Pragma("unroll")                                                       \
        for (int n_ = 0; n_ < 4; ++n_) {                                        \
            acc[m_][n_] = __builtin_amdgcn_mfma_f32_16x16x32_bf16(              \
                fxm_[m_], fbw_[n_], acc[m_][n_], 0, 0, 0);                      \
            acc[m_][n_] = __builtin_amdgcn_mfma_f32_16x16x32_bf16(              \
                fna_[m_], fba_[n_], acc[m_][n_], 0, 0, 0);                      \
        }                                                                       \
    __builtin_amdgcn_s_setprio(0); } while (0)

// out[b][o] = sum_i [ xm(b,i)*W(i,o) + (-|x(b,i)|)*(0.1|W(i,o)|) ] + 1e-5
__global__ __launch_bounds__(512) void gemm_fused(const float* __restrict__ x,
                                                  const unsigned short* __restrict__ Bw_g,
                                                  const unsigned short* __restrict__ Ba_g,
                                                  float* __restrict__ C) {
    extern __shared__ __align__(16) unsigned short smem[];
    unsigned short* sA = smem;                    // [2][A_BUF_E]
    unsigned short* sB = smem + 2 * A_BUF_E;      // [2][B_BUF_E]

    // XCD colocation (R3-verified: FETCH at compulsory minimum)
    int bid = blockIdx.x;
    int xcd = bid & 7;
    int idx = bid >> 3;            // 0..31
    int by  = xcd * 4 + (idx >> 3);
    int bx  = idx & 7;
    int row0 = by * BM;
    int col0 = bx * BN;

    int tid  = threadIdx.x;
    int lane = tid & 63;
    int w    = tid >> 6;           // 0..7
    int wr   = w >> 1;             // 0..3
    int wc   = w & 1;              // 0..1
    int lr   = lane & 15;
    int lq   = lane >> 4;          // 0..3
    int rowA = wr * 64 + lr;
    int rowB = wc * 64 + lr;

    // A-staging thread geometry: 512 threads cover 256 rows x 32 i (16 f32 each)
    int r_    = tid >> 1;                       // row 0..255
    int xcol_ = (tid & 1) * 16;                 // i-offset within 32
    int sw_   = (r_ ^ (r_ >> 2)) & 3;
    int s0_   = (tid & 1) * 2;
    int offA0_ = r_ * IS + ((s0_    ) ^ sw_) * 8;
    int offA1_ = r_ * IS + ((s0_ + 1) ^ sw_) * 8;

    f32x4 acc[4][4];
    #pragma unroll
    for (int m = 0; m < 4; ++m)
        #pragma unroll
        for (int n = 0; n < 4; ++n)
            acc[m][n] = (f32x4){0.f, 0.f, 0.f, 0.f};

    float4 x0[4], x1[4];   // x(even) / x(odd) register sets

    // ---- prologue: x(0), x(1) in flight; B(0) staged; bufA[0] written ----
    ISSUE_X(x0, 0);
    ISSUE_X(x1, 1);
    stageB(Bw_g, sB,            col0, 0, 0, tid);
    stageB(Bw_g, sB,            col0, 0, 1, tid);
    stageB(Ba_g, sB + B_MAT_E,  col0, 0, 0, tid);
    stageB(Ba_g, sB + B_MAT_E,  col0, 0, 1, tid);
    CVT_STORE(x0, sA);                      // compiler waits x0; writes bufA[0]
    asm volatile("s_waitcnt vmcnt(0)" ::: "memory");    // B(0) + x(1) resident
    asm volatile("s_waitcnt lgkmcnt(0)" ::: "memory");
    __builtin_amdgcn_s_barrier();

    for (int T = 0; T < 31; ++T) {
        unsigned short* bb  = sB + (T & 1) * B_BUF_E;
        unsigned short* bbs = sB + ((T & 1) ^ 1) * B_BUF_E;
        int t = 2 * T;
        int i1 = (T + 1) * 64;

        // ---- even iter t: read bufA[0], kk=0; issue x(t+2)->x0; stage B(T+1) ----
        ISSUE_X(x0, t + 2);
        stageB(Bw_g, bbs,           col0, i1, 0, tid);
        stageB(Bw_g, bbs,           col0, i1, 1, tid);
        stageB(Ba_g, bbs + B_MAT_E, col0, i1, 0, tid);
        stageB(Ba_g, bbs + B_MAT_E, col0, i1, 1, tid);
        FRAGS_MFMA(sA, bb, 0);
        CVT_STORE(x1, sA + A_BUF_E);        // x(t+1) -> bufA[1]
        asm volatile("s_waitcnt lgkmcnt(0)" ::: "memory");
        __builtin_amdgcn_s_barrier();

        // ---- odd iter t+1: read bufA[1], kk=1; issue x(t+3)->x1 ----
        ISSUE_X(x1, t + 3);
        FRAGS_MFMA(sA + A_BUF_E, bb, 1);
        CVT_STORE(x0, sA);                  // x(t+2) -> bufA[0]
        // drain B(T+1) (resident for next super-tile); keep x(t+3) in flight
        asm volatile("s_waitcnt vmcnt(4)" ::: "memory");
        asm volatile("s_waitcnt lgkmcnt(0)" ::: "memory");
        __builtin_amdgcn_s_barrier();
    }

    // ---- tail: t=62 (T=31, kk=0) ----
    {
        unsigned short* bb = sB + (31 & 1) * B_BUF_E;
        FRAGS_MFMA(sA, bb, 0);
        CVT_STORE(x1, sA + A_BUF_E);        // x(63) -> bufA[1]
        asm volatile("s_waitcnt lgkmcnt(0)" ::: "memory");
        __builtin_amdgcn_s_barrier();
        // ---- t=63 (kk=1) ----
        FRAGS_MFMA(sA + A_BUF_E, bb, 1);
    }

    // epilogue: C/D layout col = lane&15, row = (lane>>4)*4 + reg
    #pragma unroll
    for (int m = 0; m < 4; ++m) {
        #pragma unroll
        for (int n = 0; n < 4; ++n) {
            int col  = col0 + wc * 64 + n * 16 + lr;
            int rowb = row0 + wr * 64 + m * 16 + lq * 4;
            #pragma unroll
            for (int j = 0; j < 4; ++j)
                C[(size_t)(rowb + j) * OUT_DIM + col] = acc[m][n][j] + 1e-5f;
        }
    }
}

extern "C" void kernel_launch(void* const* d_in, const int* in_sizes, int n_in,
                              void* d_out, int out_size, void* d_ws, size_t ws_size,
                              hipStream_t stream) {
    const float* x = (const float*)d_in[0];
    const float* W = (const float*)d_in[1];
    float* out = (float*)d_out;

    unsigned short* Bw = (unsigned short*)d_ws;                                   // 4 MB
    unsigned short* Ba = (unsigned short*)d_ws + (size_t)OUT_DIM * IN_DIM;        // +4 MB

    (void)hipFuncSetAttribute((const void*)gemm_fused,
                              hipFuncAttributeMaxDynamicSharedMemorySize, LDS_BYTES);

    prep_w<<<dim3(OUT_DIM / 32, IN_DIM / 32), dim3(32, 8), 0, stream>>>(W, Bw, Ba);
    gemm_fused<<<(B_DIM / BM) * (OUT_DIM / BN), 512, LDS_BYTES, stream>>>(x, Bw, Ba, out);
}